// Round 13
// baseline (80.330 us; speedup 1.0000x reference)
//
#include <hip/hip_runtime.h>

#define LN 262144
#define LMASK 262143
#define NCH 64
#define NBF 512     // fwd blocks
#define INV_L (1.0f/262144.0f)
#define BSTR 38     // fwd LDS stride (halfs)
#define ISTR 138    // inv Bs stride (halfs)

typedef short short8 __attribute__((ext_vector_type(8)));
typedef float f32x4 __attribute__((ext_vector_type(4)));

union s8i4 { int4 i; short8 s; };

// pack two f32 -> two bf16 (truncation) in ONE v_perm_b32
static __device__ __forceinline__ unsigned pkbf(float lo, float hi) {
    union { float f; unsigned u; } a, b; a.f = lo; b.f = hi;
    return __builtin_amdgcn_perm(b.u, a.u, 0x07060302u);
}
static __device__ __forceinline__ short8 pk8(const float* v) {
    s8i4 cv;
    cv.i = make_int4(pkbf(v[0], v[1]), pkbf(v[2], v[3]),
                     pkbf(v[4], v[5]), pkbf(v[6], v[7]));
    return cv.s;
}
static __device__ __forceinline__ unsigned short f2bf_t(float x) {
    union { float f; unsigned u; } v; v.f = x;
    return (unsigned short)(v.u >> 16);
}
static __device__ __forceinline__ float bf2f(unsigned short b) {
    union { unsigned u; float f; } v; v.u = ((unsigned)b) << 16;
    return v.f;
}
static __device__ __forceinline__ float fsin01(float rev) {
    float r; asm("v_sin_f32 %0, %1" : "=v"(r) : "v"(rev)); return r;
}
static __device__ __forceinline__ float fcos01(float rev) {
    float r; asm("v_cos_f32 %0, %1" : "=v"(r) : "v"(rev)); return r;
}

// ================= K1: forward DFT partials via MFMA =================
// 512 blocks x 256 thr (R8-proven 32-row double-buffer, 3-deep pipeline).
// part_w[b*4096 + k*64 + i] = u32( Re_bf16 | Im_bf16<<16 ).
__global__ __launch_bounds__(256, 2) void fno_fwd(const float* __restrict__ u,
                                                  unsigned* __restrict__ part_w) {
    __shared__ __align__(16) unsigned short Bt[2][64 * BSTR];
    const int tid = threadIdx.x;
    const int lane = tid & 63;
    const int w = tid >> 6;
    const int l15 = lane & 15;
    const int hk = lane >> 4;
    const int kkst = tid >> 3;   // staging row 0..31
    const int gst = tid & 7;     // staging channel group
    const int n0 = blockIdx.x * 512;
    const int ksteps = 16;
    const int m = w * 16 + l15;  // this lane's mode

    float cR[8], nsR[8];
    #pragma unroll
    for (int j = 0; j < 8; ++j) {
        int ph = (m * (n0 + hk * 8 + j)) & LMASK;
        cR[j] = fcos01((float)ph * INV_L);
        nsR[j] = -fsin01((float)ph * INV_L);
    }
    float cD, sD;
    {
        int ph = (m * 32) & LMASK;
        cD = fcos01((float)ph * INV_L);
        sD = fsin01((float)ph * INV_L);
    }

    f32x4 accC[4], accS[4];
    #pragma unroll
    for (int t = 0; t < 4; ++t) { accC[t] = (f32x4){0,0,0,0}; accS[t] = (f32x4){0,0,0,0}; }

    const float* __restrict__ ub = u + (size_t)(n0 + kkst) * NCH + gst * 8;
    const size_t tstep = 32 * NCH;

#define STAGE(BUF, VA, VB) do {                                            \
        float uv_[8] = {(VA).x, (VA).y, (VA).z, (VA).w,                    \
                        (VB).x, (VB).y, (VB).z, (VB).w};                   \
        _Pragma("unroll")                                                  \
        for (int q_ = 0; q_ < 8; ++q_)                                     \
            Bt[BUF][(gst * 8 + q_) * BSTR + kkst] = f2bf_t(uv_[q_]);       \
    } while (0)

    // pipeline: regA = tile to stage next, regB = tile behind it
    float4 a0 = *(const float4*)(ub);
    float4 a1 = *(const float4*)(ub + 4);
    float4 b0 = *(const float4*)(ub + tstep);
    float4 b1 = *(const float4*)(ub + tstep + 4);
    STAGE(0, a0, a1);
    a0 = b0; a1 = b1;
    b0 = *(const float4*)(ub + 2 * tstep);
    b1 = *(const float4*)(ub + 2 * tstep + 4);

    for (int t = 0; t < ksteps; ++t) {
        __syncthreads();
        if (t + 1 < ksteps)
            STAGE((t + 1) & 1, a0, a1);
        a0 = b0; a1 = b1;
        if (t + 3 < ksteps) {
            const float* pn = ub + (size_t)(t + 3) * tstep;
            b0 = *(const float4*)(pn);
            b1 = *(const float4*)(pn + 4);
        }
        const short8 aC = pk8(cR);
        const short8 aS = pk8(nsR);
        #pragma unroll
        for (int j = 0; j < 8; ++j) {   // advance rotation by 32 rows
            float c2 = cR[j] * cD + nsR[j] * sD;
            nsR[j] = nsR[j] * cD - cR[j] * sD;
            cR[j] = c2;
        }
        const unsigned short* bt = Bt[t & 1];
        #pragma unroll
        for (int tn = 0; tn < 4; ++tn) {
            const short8 bf = *(const short8*)&bt[(tn * 16 + l15) * BSTR + hk * 8];
            accC[tn] = __builtin_amdgcn_mfma_f32_16x16x32_bf16(aC, bf, accC[tn], 0, 0, 0);
            accS[tn] = __builtin_amdgcn_mfma_f32_16x16x32_bf16(aS, bf, accS[tn], 0, 0, 0);
        }
    }
#undef STAGE
    // C/D: col=lane&15, row=(lane>>4)*4+reg; pack (Re,Im) -> u32
    unsigned* basew = part_w + (size_t)blockIdx.x * 4096;
    #pragma unroll
    for (int tn = 0; tn < 4; ++tn) {
        #pragma unroll
        for (int r = 0; r < 4; ++r) {
            int k = w * 16 + hk * 4 + r;
            int i = tn * 16 + l15;
            basew[k * 64 + i] = pkbf(accC[tn][r], accS[tn][r]);
        }
    }
}

// ================= K2: reduce packed partials -> uhat (full chip) =================
__global__ __launch_bounds__(256) void fno_red(const unsigned* __restrict__ part_w,
                                               float* __restrict__ uhat) {
    __shared__ float redR[16][17], redI[16][17];
    const int tid = threadIdx.x;
    const int c = tid & 15;
    const int h = tid >> 4;
    const int j0 = blockIdx.x * 16;

    float aR = 0.f, aI = 0.f;
    #pragma unroll 8
    for (int b = h; b < NBF; b += 16) {
        unsigned v = part_w[(size_t)b * 4096 + j0 + c];
        aR += bf2f((unsigned short)(v & 0xffff));
        aI += bf2f((unsigned short)(v >> 16));
    }
    redR[h][c] = aR;
    redI[h][c] = aI;
    __syncthreads();
    if (tid < 32) {
        const int cc = tid & 15;
        float s = 0.f;
        if (tid < 16) {
            #pragma unroll
            for (int hh = 0; hh < 16; ++hh) s += redR[hh][cc];
            uhat[j0 + cc] = s;
        } else {
            #pragma unroll
            for (int hh = 0; hh < 16; ++hh) s += redI[hh][cc];
            uhat[4096 + j0 + cc] = s;
        }
    }
}

// ================= K3: Kc apply (blocks 0..63) + z_local (block 64) =================
__global__ __launch_bounds__(256) void fno_coef(const float* __restrict__ uhat,
                                                const float* __restrict__ Kt,
                                                const float* __restrict__ W,
                                                const float* __restrict__ u,
                                                const float* __restrict__ y,
                                                float* __restrict__ coef) {
    __shared__ float sm[640];
    const int tid = threadIdx.x;
    const int o = tid & 63;
    const int q = tid >> 6;
    if (blockIdx.x == 64) {
        float* zl4 = sm;
        const int idx = (int)(y[0] * (float)LN);
        float zl = 0.f;
        #pragma unroll 4
        for (int ii = q * 16; ii < q * 16 + 16; ++ii)
            zl = fmaf(W[o * 64 + ii], u[(size_t)idx * 64 + ii], zl);
        zl4[q * 64 + o] = zl;
        __syncthreads();
        if (tid < 64)
            coef[8192 + tid] = zl4[tid] + zl4[64 + tid] + zl4[128 + tid] + zl4[192 + tid];
        return;
    }
    const int k = blockIdx.x;
    float* uh = sm;            // [128]
    float* zr4 = sm + 128;     // [4][64]
    float* zi4 = zr4 + 256;
    if (tid < 128) uh[tid] = uhat[(tid >> 6) * 4096 + k * 64 + (tid & 63)];
    __syncthreads();
    float zr = 0.f, zi = 0.f;
    #pragma unroll 4
    for (int ii = q * 16; ii < q * 16 + 16; ++ii) {
        float k0v = Kt[(size_t)(ii * 64 + o) * 64 + k];
        float k1v = Kt[262144 + (size_t)(ii * 64 + o) * 64 + k];
        zr = fmaf(uh[ii], k0v, fmaf(-uh[64 + ii], k1v, zr));
        zi = fmaf(uh[ii], k1v, fmaf(uh[64 + ii], k0v, zi));
    }
    zr4[q * 64 + o] = zr;
    zi4[q * 64 + o] = zi;
    __syncthreads();
    if (tid < 64) {
        float zrs = zr4[tid] + zr4[64 + tid] + zr4[128 + tid] + zr4[192 + tid];
        float zis = zi4[tid] + zi4[64 + tid] + zi4[128 + tid] + zi4[192 + tid];
        if (k == 0) {
            coef[tid] = zrs * INV_L;    // DC: only Re enters irfft
            coef[4096 + tid] = 0.f;
        } else {
            coef[k * 64 + tid] = 2.f * zrs * INV_L;
            coef[4096 + k * 64 + tid] = -2.f * zis * INV_L;
        }
    }
}

// ================= K4: inverse transform (operand-swapped, xpose-free) =================
// A = coef fragments (channels on l15, reg-hoisted), B = trig (out-rows on l15).
// D row = channel-local -> acc[tn] = 4 consecutive channels of out-row (nbase+l15):
// direct float4 store, NO LDS transpose, no per-iter barriers.
__global__ __launch_bounds__(256, 3) void fno_inv(const float* __restrict__ coef,
                                                  float* __restrict__ out) {
    __shared__ __align__(16) unsigned short Bs[64 * ISTR];  // [ch][cos 0..63 | sin 0..63]
    __shared__ float zloc[64];
    const int tid = threadIdx.x;
    const int lane = tid & 63;
    const int w = tid >> 6;
    const int l15 = lane & 15;
    const int hk = lane >> 4;

    for (int e = tid; e < 4096; e += 256) {
        int mm = e >> 6, ch = e & 63;
        Bs[ch * ISTR + mm] = f2bf_t(coef[e]);
        Bs[ch * ISTR + 64 + mm] = f2bf_t(coef[4096 + e]);
    }
    if (tid < 64) zloc[tid] = coef[8192 + tid];
    __syncthreads();

    // A-fragments (coef), p-invariant, hoisted to registers once.
    // afr[ks][tn]: A[ch = tn*16 + l15][mode-slot = hk*8+j], ks: 0,1=cos halves, 2,3=sin halves
    short8 afr[4][4];
    #pragma unroll
    for (int ks = 0; ks < 4; ++ks)
        #pragma unroll
        for (int tn = 0; tn < 4; ++tn)
            afr[ks][tn] = *(const short8*)&Bs[(tn * 16 + l15) * ISTR + ks * 32 + hk * 8];
    // z_local per-lane: channels tn*16 + hk*4 .. +3
    float4 zv[4];
    #pragma unroll
    for (int tn = 0; tn < 4; ++tn)
        zv[tn] = *(const float4*)&zloc[tn * 16 + hk * 4];

    for (int p = 0; p < 4; ++p) {
        const int nbase = blockIdx.x * 256 + (p * 4 + w) * 16;
        const int row = nbase + l15;
        float cstp = fcos01((float)row * INV_L);
        float sstp = fsin01((float)row * INV_L);

        // B-fragments (trig): B[mode-slot = hk*8+jj][out-row = l15]
        short8 bF[4];
        #pragma unroll
        for (int h = 0; h < 2; ++h) {
            const int m0 = h * 32 + hk * 8;
            const int ph = (row * m0) & LMASK;
            float c = fcos01((float)ph * INV_L);
            float s = fsin01((float)ph * INV_L);
            float cv[8], sv[8];
            #pragma unroll
            for (int jj = 0; jj < 8; ++jj) {
                cv[jj] = c; sv[jj] = s;
                float c2 = c * cstp - s * sstp;
                s = fmaf(s, cstp, c * sstp);
                c = c2;
            }
            bF[h] = pk8(cv);
            bF[2 + h] = pk8(sv);
        }

        f32x4 acc[4];
        #pragma unroll
        for (int tn = 0; tn < 4; ++tn) acc[tn] = (f32x4){0,0,0,0};
        #pragma unroll
        for (int ks = 0; ks < 4; ++ks)
            #pragma unroll
            for (int tn = 0; tn < 4; ++tn)
                acc[tn] = __builtin_amdgcn_mfma_f32_16x16x32_bf16(afr[ks][tn], bF[ks], acc[tn], 0, 0, 0);

        float* po = out + (size_t)row * NCH;
        #pragma unroll
        for (int tn = 0; tn < 4; ++tn) {
            float4 v = make_float4(acc[tn][0] + zv[tn].x, acc[tn][1] + zv[tn].y,
                                   acc[tn][2] + zv[tn].z, acc[tn][3] + zv[tn].w);
            *(float4*)(po + tn * 16 + hk * 4) = v;
        }
    }
}

extern "C" void kernel_launch(void* const* d_in, const int* in_sizes, int n_in,
                              void* d_out, int out_size, void* d_ws, size_t ws_size,
                              hipStream_t stream) {
    const float* u = (const float*)d_in[0];
    const float* y = (const float*)d_in[1];
    const float* K = (const float*)d_in[2];
    const float* W = (const float*)d_in[3];
    float* out = (float*)d_out;

    // ws: part_w u32[512*4096] @0 (8 MiB) | uhat f32 8192 @8 MiB | coef f32 8256
    unsigned* part_w = (unsigned*)d_ws;
    float* uhat = (float*)((char*)d_ws + 8388608);
    float* coef = uhat + 8192;

    fno_fwd<<<NBF, 256, 0, stream>>>(u, part_w);
    fno_red<<<256, 256, 0, stream>>>(part_w, uhat);
    fno_coef<<<65, 256, 0, stream>>>(uhat, K, W, u, y, coef);
    fno_inv<<<1024, 256, 0, stream>>>(coef, out);
}

// Round 14
// 62.224 us; speedup vs baseline: 1.2910x; 1.2910x over previous
//
#include <hip/hip_runtime.h>

#define LN 262144
#define LMASK 262143
#define NCH 64
#define NBF 512     // fwd blocks
#define INV_L (1.0f/262144.0f)
#define BSTR 38     // fwd LDS stride (halfs)
#define ISTR 138    // inv Bs stride (halfs)
#define XST 67      // inv xpose row stride (floats): write<=2-way, read 2x min

typedef short short8 __attribute__((ext_vector_type(8)));
typedef float f32x4 __attribute__((ext_vector_type(4)));

union s8i4 { int4 i; short8 s; };

// pack two f32 -> two bf16 (truncation) in ONE v_perm_b32
static __device__ __forceinline__ unsigned pkbf(float lo, float hi) {
    union { float f; unsigned u; } a, b; a.f = lo; b.f = hi;
    return __builtin_amdgcn_perm(b.u, a.u, 0x07060302u);
}
static __device__ __forceinline__ short8 pk8(const float* v) {
    s8i4 cv;
    cv.i = make_int4(pkbf(v[0], v[1]), pkbf(v[2], v[3]),
                     pkbf(v[4], v[5]), pkbf(v[6], v[7]));
    return cv.s;
}
static __device__ __forceinline__ unsigned short f2bf_t(float x) {
    union { float f; unsigned u; } v; v.f = x;
    return (unsigned short)(v.u >> 16);
}
static __device__ __forceinline__ float bf2f(unsigned short b) {
    union { unsigned u; float f; } v; v.u = ((unsigned)b) << 16;
    return v.f;
}
static __device__ __forceinline__ float fsin01(float rev) {
    float r; asm("v_sin_f32 %0, %1" : "=v"(r) : "v"(rev)); return r;
}
static __device__ __forceinline__ float fcos01(float rev) {
    float r; asm("v_cos_f32 %0, %1" : "=v"(r) : "v"(rev)); return r;
}

// ================= K1: forward DFT partials via MFMA =================
// 512 blocks x 256 thr (32-row double-buffer, 3-deep pipeline).
// part_w[b*4096 + k*64 + i] = u32( Re_bf16 | Im_bf16<<16 ).
__global__ __launch_bounds__(256, 2) void fno_fwd(const float* __restrict__ u,
                                                  unsigned* __restrict__ part_w) {
    __shared__ __align__(16) unsigned short Bt[2][64 * BSTR];
    const int tid = threadIdx.x;
    const int lane = tid & 63;
    const int w = tid >> 6;
    const int l15 = lane & 15;
    const int hk = lane >> 4;
    const int kkst = tid >> 3;   // staging row 0..31
    const int gst = tid & 7;     // staging channel group
    const int n0 = blockIdx.x * 512;
    const int ksteps = 16;
    const int m = w * 16 + l15;  // this lane's mode

    float cR[8], nsR[8];
    #pragma unroll
    for (int j = 0; j < 8; ++j) {
        int ph = (m * (n0 + hk * 8 + j)) & LMASK;
        cR[j] = fcos01((float)ph * INV_L);
        nsR[j] = -fsin01((float)ph * INV_L);
    }
    float cD, sD;
    {
        int ph = (m * 32) & LMASK;
        cD = fcos01((float)ph * INV_L);
        sD = fsin01((float)ph * INV_L);
    }

    f32x4 accC[4], accS[4];
    #pragma unroll
    for (int t = 0; t < 4; ++t) { accC[t] = (f32x4){0,0,0,0}; accS[t] = (f32x4){0,0,0,0}; }

    const float* __restrict__ ub = u + (size_t)(n0 + kkst) * NCH + gst * 8;
    const size_t tstep = 32 * NCH;

#define STAGE(BUF, VA, VB) do {                                            \
        float uv_[8] = {(VA).x, (VA).y, (VA).z, (VA).w,                    \
                        (VB).x, (VB).y, (VB).z, (VB).w};                   \
        _Pragma("unroll")                                                  \
        for (int q_ = 0; q_ < 8; ++q_)                                     \
            Bt[BUF][(gst * 8 + q_) * BSTR + kkst] = f2bf_t(uv_[q_]);       \
    } while (0)

    float4 a0 = *(const float4*)(ub);
    float4 a1 = *(const float4*)(ub + 4);
    float4 b0 = *(const float4*)(ub + tstep);
    float4 b1 = *(const float4*)(ub + tstep + 4);
    STAGE(0, a0, a1);
    a0 = b0; a1 = b1;
    b0 = *(const float4*)(ub + 2 * tstep);
    b1 = *(const float4*)(ub + 2 * tstep + 4);

    for (int t = 0; t < ksteps; ++t) {
        __syncthreads();
        if (t + 1 < ksteps)
            STAGE((t + 1) & 1, a0, a1);
        a0 = b0; a1 = b1;
        if (t + 3 < ksteps) {
            const float* pn = ub + (size_t)(t + 3) * tstep;
            b0 = *(const float4*)(pn);
            b1 = *(const float4*)(pn + 4);
        }
        const short8 aC = pk8(cR);
        const short8 aS = pk8(nsR);
        #pragma unroll
        for (int j = 0; j < 8; ++j) {   // advance rotation by 32 rows
            float c2 = cR[j] * cD + nsR[j] * sD;
            nsR[j] = nsR[j] * cD - cR[j] * sD;
            cR[j] = c2;
        }
        const unsigned short* bt = Bt[t & 1];
        #pragma unroll
        for (int tn = 0; tn < 4; ++tn) {
            const short8 bf = *(const short8*)&bt[(tn * 16 + l15) * BSTR + hk * 8];
            accC[tn] = __builtin_amdgcn_mfma_f32_16x16x32_bf16(aC, bf, accC[tn], 0, 0, 0);
            accS[tn] = __builtin_amdgcn_mfma_f32_16x16x32_bf16(aS, bf, accS[tn], 0, 0, 0);
        }
    }
#undef STAGE
    unsigned* basew = part_w + (size_t)blockIdx.x * 4096;
    #pragma unroll
    for (int tn = 0; tn < 4; ++tn) {
        #pragma unroll
        for (int r = 0; r < 4; ++r) {
            int k = w * 16 + hk * 4 + r;
            int i = tn * 16 + l15;
            basew[k * 64 + i] = pkbf(accC[tn][r], accS[tn][r]);
        }
    }
}

// ================= K2: reduce packed partials -> uhat (full chip) =================
__global__ __launch_bounds__(256) void fno_red(const unsigned* __restrict__ part_w,
                                               float* __restrict__ uhat) {
    __shared__ float redR[16][17], redI[16][17];
    const int tid = threadIdx.x;
    const int c = tid & 15;
    const int h = tid >> 4;
    const int j0 = blockIdx.x * 16;

    float aR = 0.f, aI = 0.f;
    #pragma unroll 8
    for (int b = h; b < NBF; b += 16) {
        unsigned v = part_w[(size_t)b * 4096 + j0 + c];
        aR += bf2f((unsigned short)(v & 0xffff));
        aI += bf2f((unsigned short)(v >> 16));
    }
    redR[h][c] = aR;
    redI[h][c] = aI;
    __syncthreads();
    if (tid < 32) {
        const int cc = tid & 15;
        float s = 0.f;
        if (tid < 16) {
            #pragma unroll
            for (int hh = 0; hh < 16; ++hh) s += redR[hh][cc];
            uhat[j0 + cc] = s;
        } else {
            #pragma unroll
            for (int hh = 0; hh < 16; ++hh) s += redI[hh][cc];
            uhat[4096 + j0 + cc] = s;
        }
    }
}

// ================= K3: Kc apply (blocks 0..63) + z_local (block 64) =================
__global__ __launch_bounds__(256) void fno_coef(const float* __restrict__ uhat,
                                                const float* __restrict__ Kt,
                                                const float* __restrict__ W,
                                                const float* __restrict__ u,
                                                const float* __restrict__ y,
                                                float* __restrict__ coef) {
    __shared__ float sm[640];
    const int tid = threadIdx.x;
    const int o = tid & 63;
    const int q = tid >> 6;
    if (blockIdx.x == 64) {
        float* zl4 = sm;
        const int idx = (int)(y[0] * (float)LN);
        float zl = 0.f;
        #pragma unroll 4
        for (int ii = q * 16; ii < q * 16 + 16; ++ii)
            zl = fmaf(W[o * 64 + ii], u[(size_t)idx * 64 + ii], zl);
        zl4[q * 64 + o] = zl;
        __syncthreads();
        if (tid < 64)
            coef[8192 + tid] = zl4[tid] + zl4[64 + tid] + zl4[128 + tid] + zl4[192 + tid];
        return;
    }
    const int k = blockIdx.x;
    float* uh = sm;            // [128]
    float* zr4 = sm + 128;     // [4][64]
    float* zi4 = zr4 + 256;
    if (tid < 128) uh[tid] = uhat[(tid >> 6) * 4096 + k * 64 + (tid & 63)];
    __syncthreads();
    float zr = 0.f, zi = 0.f;
    #pragma unroll 4
    for (int ii = q * 16; ii < q * 16 + 16; ++ii) {
        float k0v = Kt[(size_t)(ii * 64 + o) * 64 + k];
        float k1v = Kt[262144 + (size_t)(ii * 64 + o) * 64 + k];
        zr = fmaf(uh[ii], k0v, fmaf(-uh[64 + ii], k1v, zr));
        zi = fmaf(uh[ii], k1v, fmaf(uh[64 + ii], k0v, zi));
    }
    zr4[q * 64 + o] = zr;
    zi4[q * 64 + o] = zi;
    __syncthreads();
    if (tid < 64) {
        float zrs = zr4[tid] + zr4[64 + tid] + zr4[128 + tid] + zr4[192 + tid];
        float zis = zi4[tid] + zi4[64 + tid] + zi4[128 + tid] + zi4[192 + tid];
        if (k == 0) {
            coef[tid] = zrs * INV_L;    // DC: only Re enters irfft
            coef[4096 + tid] = 0.f;
        } else {
            coef[k * 64 + tid] = 2.f * zrs * INV_L;
            coef[4096 + k * 64 + tid] = -2.f * zis * INV_L;
        }
    }
}

// ================= K4: inverse (operand-swapped MFMA + pipelined store-xpose) =======
// MFMA loop is LDS-free (coef A-fragments reg-hoisted; trig B generated per-lane).
// Store path: per-wave double-buffered xpose; read of buf[p-1] issues BEFORE
// write of buf[p] -> compiler's auto-wait is lgkmcnt(16) (drains only the reads),
// and the write->read gap spans one full compute phase. Stores: 4 rows x 256 B
// fully contiguous per instruction (no partial-line amplification).
__global__ __launch_bounds__(256) void fno_inv(const float* __restrict__ coef,
                                               float* __restrict__ out) {
    __shared__ __align__(16) char ismem[34816];
    unsigned short* Bs = (unsigned short*)ismem;      // prologue only (aliased below)
    float* zloc = (float*)(ismem + 34304);            // 64 f, persistent
    const int tid = threadIdx.x;
    const int lane = tid & 63;
    const int w = tid >> 6;
    const int l15 = lane & 15;
    const int hk = lane >> 4;

    for (int e = tid; e < 4096; e += 256) {
        int mm = e >> 6, ch = e & 63;
        Bs[ch * ISTR + mm] = f2bf_t(coef[e]);
        Bs[ch * ISTR + 64 + mm] = f2bf_t(coef[4096 + e]);
    }
    if (tid < 64) zloc[tid] = coef[8192 + tid];
    __syncthreads();

    // A-fragments (coef), p-invariant, hoisted once.
    short8 afr[4][4];
    #pragma unroll
    for (int ks = 0; ks < 4; ++ks)
        #pragma unroll
        for (int tn = 0; tn < 4; ++tn)
            afr[ks][tn] = *(const short8*)&Bs[(tn * 16 + l15) * ISTR + ks * 32 + hk * 8];
    __syncthreads();   // all waves done with Bs -> xpose buffers may alias it

    float* xp0 = (float*)ismem + w * (2 * 16 * XST);
    float* xp1 = xp0 + 16 * XST;

    const int rl = lane >> 4;        // store: row-in-quad
    const int cq = lane & 15;        // store: 16B channel slot
    const float4 zvs = *(const float4*)&zloc[cq * 4];

    int prev_nbase = 0;
    float4 rv[4];

    for (int p = 0; p < 4; ++p) {
        const int nbase = blockIdx.x * 256 + (p * 4 + w) * 16;
        const int row = nbase + l15;
        float cstp = fcos01((float)row * INV_L);
        float sstp = fsin01((float)row * INV_L);

        // B-fragments (trig): rows on l15
        short8 bF[4];
        #pragma unroll
        for (int h = 0; h < 2; ++h) {
            const int m0 = h * 32 + hk * 8;
            const int ph = (row * m0) & LMASK;
            float c = fcos01((float)ph * INV_L);
            float s = fsin01((float)ph * INV_L);
            float cv[8], sv[8];
            #pragma unroll
            for (int jj = 0; jj < 8; ++jj) {
                cv[jj] = c; sv[jj] = s;
                float c2 = c * cstp - s * sstp;
                s = fmaf(s, cstp, c * sstp);
                c = c2;
            }
            bF[h] = pk8(cv);
            bF[2 + h] = pk8(sv);
        }

        f32x4 acc[4];
        #pragma unroll
        for (int tn = 0; tn < 4; ++tn) acc[tn] = (f32x4){0,0,0,0};
        #pragma unroll
        for (int ks = 0; ks < 4; ++ks)
            #pragma unroll
            for (int tn = 0; tn < 4; ++tn)
                acc[tn] = __builtin_amdgcn_mfma_f32_16x16x32_bf16(afr[ks][tn], bF[ks], acc[tn], 0, 0, 0);

        // read previous buffer FIRST (its writes were covered by this compute)
        if (p > 0) {
            const float* xr = (p & 1) ? xp0 : xp1;
            #pragma unroll
            for (int rg = 0; rg < 4; ++rg)
                rv[rg] = *(const float4*)&xr[(rg * 4 + rl) * XST + cq * 4];
        }
        // then write current acc (lane's 4 contiguous channels per group)
        {
            float* xw = (p & 1) ? xp1 : xp0;
            #pragma unroll
            for (int tn = 0; tn < 4; ++tn)
                #pragma unroll
                for (int r = 0; r < 4; ++r)
                    xw[l15 * XST + tn * 16 + hk * 4 + r] = acc[tn][r];
        }
        // store previous iteration's rows: 4 rows x 256 B contiguous per instr
        if (p > 0) {
            #pragma unroll
            for (int rg = 0; rg < 4; ++rg) {
                float4 v = make_float4(rv[rg].x + zvs.x, rv[rg].y + zvs.y,
                                       rv[rg].z + zvs.z, rv[rg].w + zvs.w);
                *(float4*)(out + (size_t)(prev_nbase + rg * 4 + rl) * NCH + cq * 4) = v;
            }
        }
        prev_nbase = nbase;
    }
    // epilogue: drain last buffer (p=3 -> xp1)
    {
        const float* xr = xp1;
        #pragma unroll
        for (int rg = 0; rg < 4; ++rg) {
            float4 v = *(const float4*)&xr[(rg * 4 + rl) * XST + cq * 4];
            v.x += zvs.x; v.y += zvs.y; v.z += zvs.z; v.w += zvs.w;
            *(float4*)(out + (size_t)(prev_nbase + rg * 4 + rl) * NCH + cq * 4) = v;
        }
    }
}

extern "C" void kernel_launch(void* const* d_in, const int* in_sizes, int n_in,
                              void* d_out, int out_size, void* d_ws, size_t ws_size,
                              hipStream_t stream) {
    const float* u = (const float*)d_in[0];
    const float* y = (const float*)d_in[1];
    const float* K = (const float*)d_in[2];
    const float* W = (const float*)d_in[3];
    float* out = (float*)d_out;

    // ws: part_w u32[512*4096] @0 (8 MiB) | uhat f32 8192 @8 MiB | coef f32 8256
    unsigned* part_w = (unsigned*)d_ws;
    float* uhat = (float*)((char*)d_ws + 8388608);
    float* coef = uhat + 8192;

    fno_fwd<<<NBF, 256, 0, stream>>>(u, part_w);
    fno_red<<<256, 256, 0, stream>>>(part_w, uhat);
    fno_coef<<<65, 256, 0, stream>>>(uhat, K, W, u, y, coef);
    fno_inv<<<1024, 256, 0, stream>>>(coef, out);
}